// Round 1
// baseline (67.347 us; speedup 1.0000x reference)
//
#include <hip/hip_runtime.h>
#include <hip/hip_bf16.h>

#define BATCH 1024
#define LEN   512
#define NTHREADS 256
#define MARGIN 1.0f

// Kernel 1: one block per sample. Compact positives/negatives into LDS,
// then accumulate hinge loss over pos x neg pairs.
__global__ __launch_bounds__(NTHREADS) void per_sample_loss(
    const float* __restrict__ scores,   // [BATCH, LEN]
    const int*   __restrict__ labels,   // [BATCH, LEN], 1 = positive
    float*       __restrict__ ws)       // [BATCH] per-sample loss
{
    __shared__ __align__(16) float pos[LEN];
    __shared__ __align__(16) float neg[LEN];
    __shared__ int cnt[2];              // [0]=n_pos, [1]=n_neg
    __shared__ float red[NTHREADS / 64];

    const int b   = blockIdx.x;
    const int tid = threadIdx.x;

    if (tid < 2) cnt[tid] = 0;
    __syncthreads();

    // Compaction: order within pos[]/neg[] is irrelevant for the sum.
    #pragma unroll
    for (int l = tid; l < LEN; l += NTHREADS) {
        float s  = scores[b * LEN + l];
        int   la = labels[b * LEN + l];
        if (la != 0) {
            int i = atomicAdd(&cnt[0], 1);
            pos[i] = s;
        } else {
            int i = atomicAdd(&cnt[1], 1);
            neg[i] = s;
        }
    }
    __syncthreads();

    const int n_pos = cnt[0];
    const int n_neg = cnt[1];

    float acc = 0.0f;
    // Each thread owns positives tid, tid+256, ...; inner loop over all
    // negatives. All lanes read the same neg[] address -> LDS broadcast
    // (conflict-free). float4 reads amortize ds_read issue cost.
    const float4* neg4 = reinterpret_cast<const float4*>(neg);
    const int n_neg4 = n_neg >> 2;
    for (int pi = tid; pi < n_pos; pi += NTHREADS) {
        const float q = MARGIN - pos[pi];
        int j4 = 0;
        for (; j4 < n_neg4; ++j4) {
            float4 n = neg4[j4];
            acc += fmaxf(0.0f, q + n.x);
            acc += fmaxf(0.0f, q + n.y);
            acc += fmaxf(0.0f, q + n.z);
            acc += fmaxf(0.0f, q + n.w);
        }
        for (int j = n_neg4 << 2; j < n_neg; ++j) {
            acc += fmaxf(0.0f, q + neg[j]);
        }
    }

    // Wave (64-lane) shuffle reduction, then LDS across the 4 waves.
    #pragma unroll
    for (int off = 32; off > 0; off >>= 1) acc += __shfl_down(acc, off, 64);
    if ((tid & 63) == 0) red[tid >> 6] = acc;
    __syncthreads();

    if (tid == 0) {
        float s = red[0] + red[1] + red[2] + red[3];
        float n_pairs = (float)n_pos * (float)n_neg;
        ws[b] = s / fmaxf(n_pairs, 1.0f);
    }
}

// Kernel 2: deterministic reduction of BATCH per-sample losses -> mean.
__global__ __launch_bounds__(NTHREADS) void reduce_batch(
    const float* __restrict__ ws, float* __restrict__ out)
{
    __shared__ float red[NTHREADS / 64];
    const int tid = threadIdx.x;

    float acc = 0.0f;
    #pragma unroll
    for (int i = tid; i < BATCH; i += NTHREADS) acc += ws[i];

    #pragma unroll
    for (int off = 32; off > 0; off >>= 1) acc += __shfl_down(acc, off, 64);
    if ((tid & 63) == 0) red[tid >> 6] = acc;
    __syncthreads();

    if (tid == 0) {
        out[0] = (red[0] + red[1] + red[2] + red[3]) * (1.0f / (float)BATCH);
    }
}

extern "C" void kernel_launch(void* const* d_in, const int* in_sizes, int n_in,
                              void* d_out, int out_size, void* d_ws, size_t ws_size,
                              hipStream_t stream) {
    const float* scores = (const float*)d_in[0];
    const int*   labels = (const int*)d_in[1];
    float*       out    = (float*)d_out;
    float*       ws     = (float*)d_ws;   // BATCH floats of scratch

    per_sample_loss<<<BATCH, NTHREADS, 0, stream>>>(scores, labels, ws);
    reduce_batch<<<1, NTHREADS, 0, stream>>>(ws, out);
}